// Round 7
// baseline (6096.780 us; speedup 1.0000x reference)
//
#include <hip/hip_runtime.h>
#include <stdint.h>
#include <stddef.h>

// Problem constants (match reference)
#define BB 128
#define SS 128
#define EE 256
#define DD 512
#define KK 16
#define LL 1906   // 1 + 127*15
#define RR 2033   // 1 + 127*16
#define NSTEP 127

// ---------------- JAX threefry2x32 (bit-exact, partitionable) ----------------
static __device__ __forceinline__ uint32_t rotl32(uint32_t v, int r) {
  return (v << r) | (v >> (32 - r));
}

static __device__ __forceinline__ void tf2x32(uint32_t k0, uint32_t k1,
                                              uint32_t x0, uint32_t x1,
                                              uint32_t &o0, uint32_t &o1) {
  uint32_t ks2 = k0 ^ k1 ^ 0x1BD11BDAu;
  x0 += k0; x1 += k1;
#define TFR(r) { x0 += x1; x1 = rotl32(x1, (r)); x1 ^= x0; }
  TFR(13) TFR(15) TFR(26) TFR(6)
  x0 += k1;  x1 += ks2 + 1u;
  TFR(17) TFR(29) TFR(16) TFR(24)
  x0 += ks2; x1 += k0 + 2u;
  TFR(13) TFR(15) TFR(26) TFR(6)
  x0 += k0;  x1 += k1 + 3u;
  TFR(17) TFR(29) TFR(16) TFR(24)
  x0 += k1;  x1 += ks2 + 4u;
  TFR(13) TFR(15) TFR(26) TFR(6)
  x0 += ks2; x1 += k0 + 5u;
#undef TFR
  o0 = x0; o1 = x1;
}

static __device__ __forceinline__ float jax_gumbel(uint32_t bits) {
  float f = __uint_as_float((bits >> 9) | 0x3F800000u) - 1.0f;
  float u = fmaxf(f, 1.17549435e-38f);
  return -logf(-logf(u));
}

// S-group (waves 0-7) LDS barrier: monotonic epoch counter, intra-CU only.
// T-group never touches it; the block-wide __syncthreads joins both groups.
static __device__ __forceinline__ void s_bar8(int* ctr, int tgt) {
  __threadfence_block();
  if ((threadIdx.x & 63) == 0)
    __hip_atomic_fetch_add(ctr, 1, __ATOMIC_RELAXED, __HIP_MEMORY_SCOPE_WORKGROUP);
  while (__hip_atomic_load(ctr, __ATOMIC_RELAXED, __HIP_MEMORY_SCOPE_WORKGROUP) < tgt) {}
  __threadfence_block();
}

// ---------------- persistent kernel: one block per batch row ----------------
__global__ __launch_bounds__(1024, 4) void rnn_gen_kernel(
    const int*   __restrict__ marker_data,   // (B,S) int32
    const float* __restrict__ time_data,     // (B,S)
    const float* __restrict__ mask_data,     // (B,S)
    const float* __restrict__ embedding,     // (50000,E)
    const int*   __restrict__ neighbor_list, // (50000,K) int32
    const float* __restrict__ neighbor_prob, // (50000,K)
    const float* __restrict__ W_te, const float* __restrict__ b_te,
    const float* __restrict__ W_el, const float* __restrict__ b_el,
    const float* __restrict__ W_ih, const float* __restrict__ b_ih,
    const float* __restrict__ W_hh, const float* __restrict__ b_hh,
    const float* __restrict__ W_time, const float* __restrict__ b_time,
    const float* __restrict__ W_mk, const float* __restrict__ b_mk,
    float* __restrict__ out)                 // 5 x (B,S) f32, concat
{
  __shared__ double s_pdA[4][DD];    // 16 KB: el partials, then ih partials
  __shared__ double s_pdB[2][DD];    //  8 KB: hh partials (pipelined across steps)
  __shared__ float  s_prob[LL];
  __shared__ float  s_logp[LL];      // incremental log-prob (matches ref's logit calc)
  __shared__ int    s_cand[LL];
  __shared__ float  s_nrec[RR];
  __shared__ float  s_vec[EE];
  __shared__ float  s_x[DD];
  __shared__ float  s_h[DD];
  __shared__ double s_edot[KK];
  __shared__ double s_rt[8];
  __shared__ double s_rm[8];
  __shared__ float  s_red_z[8];
  __shared__ int    s_red_i[8];
  __shared__ int    s_neigh[KK];
  __shared__ float  s_last_t;
  __shared__ int    s_last_m;
  __shared__ int    s_chosen;
  __shared__ float  s_newt;
  __shared__ uint32_t s_k0, s_k1;
  __shared__ int    s_ctr;

  const int b   = blockIdx.x;
  const int tid = threadIdx.x;

  // ---- A0: state init
  for (int i = tid; i < LL; i += 1024) { s_prob[i] = 0.0f; s_logp[i] = -1e30f; s_cand[i] = 0; }
  for (int i = tid; i < RR; i += 1024) s_nrec[i] = 1.0f;
  if (tid < DD) s_h[tid] = 0.0f;
  if (tid < 2 * DD) ((double*)s_pdB)[tid] = 0.0;   // hh partials for h0 = 0
  if (tid == 0) {
    s_ctr = 0;
    int   m0 = marker_data[b * SS];
    float t0 = time_data[b * SS];
    s_cand[0] = m0; s_prob[0] = 1.0f; s_logp[0] = 0.0f;   // log(1)
    s_last_m = m0; s_last_t = t0; s_chosen = 0;
    out[0 * BB * SS + b * SS] = (float)m0;
    out[1 * BB * SS + b * SS] = t0;
    out[2 * BB * SS + b * SS] = mask_data[b * SS];
    out[3 * BB * SS + b * SS] = 1.0f;
    out[4 * BB * SS + b * SS] = 1.0f;
  }
  __syncthreads();

  // ---- A0b: vec(0), bookkeeping(0), e-dots(0)
  {
    const int   m  = s_last_m;
    const float lt = s_last_t;
    if (tid < EE) {
      float te = __fadd_rn(__fmul_rn(lt, W_te[tid]), b_te[tid]);
      s_vec[tid] = __fadd_rn(embedding[(size_t)m * EE + tid], __fmul_rn(0.1f, te));
    }
    if (tid >= 256 && tid < 512) {
      int k = (tid - 256) >> 4, l16 = tid & 15;
      int nb = neighbor_list[(size_t)m * KK + k];
      if (l16 == 0) {
        s_neigh[k] = nb;
        s_nrec[1 + 0 * KK + k] = neighbor_prob[(size_t)m * KK + k];
        if (k >= 1) s_cand[1 + 0 * (KK - 1) + (k - 1)] = nb;
      }
      const float4* er = (const float4*)(embedding + (size_t)nb * EE) + 4 * l16;
      const float4* wm = (const float4*)W_mk + 4 * l16;
      float4 e0 = er[0], e1 = er[1], e2 = er[2], e3 = er[3];
      float4 m0_ = wm[0], m1_ = wm[1], m2_ = wm[2], m3_ = wm[3];
      double acc = 0.0;
      acc = fma((double)e0.x, (double)m0_.x, acc); acc = fma((double)e0.y, (double)m0_.y, acc);
      acc = fma((double)e0.z, (double)m0_.z, acc); acc = fma((double)e0.w, (double)m0_.w, acc);
      acc = fma((double)e1.x, (double)m1_.x, acc); acc = fma((double)e1.y, (double)m1_.y, acc);
      acc = fma((double)e1.z, (double)m1_.z, acc); acc = fma((double)e1.w, (double)m1_.w, acc);
      acc = fma((double)e2.x, (double)m2_.x, acc); acc = fma((double)e2.y, (double)m2_.y, acc);
      acc = fma((double)e2.z, (double)m2_.z, acc); acc = fma((double)e2.w, (double)m2_.w, acc);
      acc = fma((double)e3.x, (double)m3_.x, acc); acc = fma((double)e3.y, (double)m3_.y, acc);
      acc = fma((double)e3.z, (double)m3_.z, acc); acc = fma((double)e3.w, (double)m3_.w, acc);
      for (int off = 8; off > 0; off >>= 1) acc += __shfl_down(acc, off, 16);
      if (l16 == 0) s_edot[k] = acc;
    }
  }
  __syncthreads();

  int sep = 0;                   // S-barrier epoch (uniform across S threads)
  const int jg2 = tid & 255;     // 2 output cols: 2*jg2, 2*jg2+1
  const int slA = tid >> 8;      // K-slice 0..3

  for (int t = 0; t < NSTEP; ++t) {
    // ---- B: el stream (all 1024 threads; 4 slices x 64 K-rows)
    {
      const int i0 = slA << 6;
      const float2* W2 = (const float2*)W_el + (size_t)i0 * 256 + jg2;
      double a0 = 0.0, a1 = 0.0;
#pragma unroll 8
      for (int i = 0; i < 64; ++i) {
        float2 w = W2[(size_t)i * 256];
        double v = (double)s_vec[i0 + i];
        a0 = fma(v, (double)w.x, a0);
        a1 = fma(v, (double)w.y, a1);
      }
      s_pdA[slA][2 * jg2] = a0; s_pdA[slA][2 * jg2 + 1] = a1;
    }
    __syncthreads();

    // ---- combine x
    if (tid < DD) {
      double d = (s_pdA[0][tid] + s_pdA[1][tid]) + (s_pdA[2][tid] + s_pdA[3][tid]);
      float z = __fadd_rn((float)d, b_el[tid]);
      s_x[tid] = (z >= 0.0f) ? z : __fmul_rn(0.01f, z);
    }
    __syncthreads();

    // ---- D: ih stream (all 1024; 4 slices x 128 K-rows)
    {
      const int i0 = slA << 7;
      const float2* W2 = (const float2*)W_ih + (size_t)i0 * 256 + jg2;
      double a0 = 0.0, a1 = 0.0;
#pragma unroll 8
      for (int i = 0; i < 128; ++i) {
        float2 w = W2[(size_t)i * 256];
        double v = (double)s_x[i0 + i];
        a0 = fma(v, (double)w.x, a0);
        a1 = fma(v, (double)w.y, a1);
      }
      s_pdA[slA][2 * jg2] = a0; s_pdA[slA][2 * jg2 + 1] = a1;
    }
    __syncthreads();

    // ---- combine h = tanh(((ih + b_ih) + hh) + b_hh); hh partials pipelined
    if (tid < DD) {
      double ih = (s_pdA[0][tid] + s_pdA[1][tid]) + (s_pdA[2][tid] + s_pdA[3][tid]);
      double hh = s_pdB[0][tid] + s_pdB[1][tid];
      float p = __fadd_rn(__fadd_rn(__fadd_rn((float)ih, b_ih[tid]), (float)hh), b_hh[tid]);
      s_h[tid] = (float)tanh((double)p);
    }
    __syncthreads();   // h(t+1) ready — SPLIT (no __syncthreads inside!)

    if (tid >= 512) {
      // ======= T group (waves 8-15): stream W_hh for NEXT step (h-only dep) =======
      if (t + 1 < NSTEP) {
        const int q  = tid - 512;
        const int j2 = q & 255;
        const int sl = q >> 8;           // 0..1
        const int i0 = sl << 8;          // 0 / 256
        const float2* W2 = (const float2*)W_hh + (size_t)i0 * 256 + j2;
        double a0 = 0.0, a1 = 0.0;
#pragma unroll 8
        for (int i = 0; i < 256; ++i) {
          float2 w = W2[(size_t)i * 256];
          double v = (double)s_h[i0 + i];
          a0 = fma(v, (double)w.x, a0);
          a1 = fma(v, (double)w.y, a1);
        }
        s_pdB[sl][2 * j2] = a0; s_pdB[sl][2 * j2 + 1] = a1;
      }
    } else {
      // ======= S group (waves 0-7): the whole serial tail, hidden under T =======
      // tail-1: h-dots (W_time, W_mk[E:])
      {
        double hv = (double)s_h[tid];
        double pt = hv * (double)W_time[tid];
        double pm = hv * (double)W_mk[EE + tid];
        for (int off = 32; off > 0; off >>= 1) {
          pt += __shfl_down(pt, off);
          pm += __shfl_down(pm, off);
        }
        if ((tid & 63) == 0) { s_rt[tid >> 6] = pt; s_rm[tid >> 6] = pm; }
      }
      ++sep; s_bar8(&s_ctr, 8 * sep);

      // tail-2: wave0 — softmax lanes 0-15 (exact f32 op order), lane16 new_t, lane17 key
      if (tid < KK) {
        double hmk = ((s_rm[0] + s_rm[1]) + (s_rm[2] + s_rm[3]))
                   + ((s_rm[4] + s_rm[5]) + (s_rm[6] + s_rm[7]));
        float sc = __fadd_rn((float)(s_edot[tid] + hmk), b_mk[0]);
        float mx = sc;
        for (int k = 0; k < KK; ++k) mx = fmaxf(mx, __shfl(sc, k));
        float ee = expf(__fsub_rn(sc, mx));
        float ssum = 0.0f;
        for (int k = 0; k < KK; ++k) ssum = __fadd_rn(ssum, __shfl(ee, k));  // ordered
        float cp = s_prob[s_chosen];
        float at = __fmul_rn(cp, __fdiv_rn(ee, ssum));
        float lp = (at > 0.0f) ? logf(fmaxf(at, 1e-38f)) : -1e30f;
        if (tid == 0) { s_prob[s_chosen] = at; s_logp[s_chosen] = lp; }
        else {
          int idx = 1 + t * (KK - 1) + (tid - 1);
          s_prob[idx] = at; s_logp[idx] = lp;
        }
      } else if (tid == 16) {
        double ht = ((s_rt[0] + s_rt[1]) + (s_rt[2] + s_rt[3]))
                  + ((s_rt[4] + s_rt[5]) + (s_rt[6] + s_rt[7]));
        float td = __fadd_rn((float)ht, b_time[0]);
        float sp = __fadd_rn(fmaxf(td, 0.0f), log1pf(expf(-fabsf(td))));
        s_newt = __fadd_rn(s_last_t, sp);
      } else if (tid == 17) {
        uint32_t o0, o1;
        tf2x32(0u, 42u, 0u, (uint32_t)t, o0, o1);
        s_k0 = o0; s_k1 = o1;
      }
      ++sep; s_bar8(&s_ctr, 8 * sep);

      // tail-3: gumbel-argmax scan (512 threads, <=4 entries each)
      {
        const int active = 16 + 15 * t;
        const uint32_t kk0 = s_k0, kk1 = s_k1;
        float bz = -3.0e38f;
        int   bi = 0x7FFFFFFF;
        for (int l = tid; l < active; l += 512) {
          uint32_t i = (uint32_t)(b * LL + l);
          uint32_t o0, o1;
          tf2x32(kk0, kk1, 0u, i, o0, o1);
          float g = jax_gumbel(o0 ^ o1);
          float z = __fadd_rn(s_logp[l], g);
          if (z > bz) { bz = z; bi = l; }   // ascending l => strict > keeps first
        }
        for (int off = 32; off > 0; off >>= 1) {
          float oz = __shfl_down(bz, off);
          int   oi = __shfl_down(bi, off);
          if (oz > bz || (oz == bz && oi < bi)) { bz = oz; bi = oi; }
        }
        if ((tid & 63) == 0) { s_red_z[tid >> 6] = bz; s_red_i[tid >> 6] = bi; }
      }
      ++sep; s_bar8(&s_ctr, 8 * sep);

      // tail-4: finalize (thread 0)
      if (tid == 0) {
        float z0 = s_red_z[0]; int i0 = s_red_i[0];
        for (int w = 1; w < 8; ++w) {
          if (s_red_z[w] > z0 || (s_red_z[w] == z0 && s_red_i[w] < i0)) {
            z0 = s_red_z[w]; i0 = s_red_i[w];
          }
        }
        int   nm = s_cand[i0];
        float nt = s_newt;
        out[0 * BB * SS + b * SS + (t + 1)] = (float)nm;
        out[1 * BB * SS + b * SS + (t + 1)] = nt;
        out[2 * BB * SS + b * SS + (t + 1)] = (nt < 1000.0f) ? 1.0f : 0.0f;
        out[3 * BB * SS + b * SS + (t + 1)] = s_nrec[i0];
        out[4 * BB * SS + b * SS + (t + 1)] = s_prob[i0];
        s_chosen = i0; s_last_m = nm; s_last_t = nt;
      }
      ++sep; s_bar8(&s_ctr, 8 * sep);

      // tail-5: vec(t+1), bookkeeping(t+1), e-dots(t+1)
      if (t + 1 < NSTEP) {
        const int   m   = s_last_m;
        const float lt2 = s_last_t;
        if (tid < EE) {
          float te = __fadd_rn(__fmul_rn(lt2, W_te[tid]), b_te[tid]);
          s_vec[tid] = __fadd_rn(embedding[(size_t)m * EE + tid], __fmul_rn(0.1f, te));
        }
        if (tid >= 256) {   // 256..511: 16 k-groups x 16 lanes
          int k = (tid - 256) >> 4, l16 = tid & 15;
          int nb = neighbor_list[(size_t)m * KK + k];
          if (l16 == 0) {
            s_neigh[k] = nb;
            s_nrec[1 + (t + 1) * KK + k] = neighbor_prob[(size_t)m * KK + k];
            if (k >= 1) s_cand[1 + (t + 1) * (KK - 1) + (k - 1)] = nb;
          }
          const float4* er = (const float4*)(embedding + (size_t)nb * EE) + 4 * l16;
          const float4* wm = (const float4*)W_mk + 4 * l16;
          float4 e0 = er[0], e1 = er[1], e2 = er[2], e3 = er[3];
          float4 m0_ = wm[0], m1_ = wm[1], m2_ = wm[2], m3_ = wm[3];
          double acc = 0.0;
          acc = fma((double)e0.x, (double)m0_.x, acc); acc = fma((double)e0.y, (double)m0_.y, acc);
          acc = fma((double)e0.z, (double)m0_.z, acc); acc = fma((double)e0.w, (double)m0_.w, acc);
          acc = fma((double)e1.x, (double)m1_.x, acc); acc = fma((double)e1.y, (double)m1_.y, acc);
          acc = fma((double)e1.z, (double)m1_.z, acc); acc = fma((double)e1.w, (double)m1_.w, acc);
          acc = fma((double)e2.x, (double)m2_.x, acc); acc = fma((double)e2.y, (double)m2_.y, acc);
          acc = fma((double)e2.z, (double)m2_.z, acc); acc = fma((double)e2.w, (double)m2_.w, acc);
          acc = fma((double)e3.x, (double)m3_.x, acc); acc = fma((double)e3.y, (double)m3_.y, acc);
          acc = fma((double)e3.z, (double)m3_.z, acc); acc = fma((double)e3.w, (double)m3_.w, acc);
          for (int off = 8; off > 0; off >>= 1) acc += __shfl_down(acc, off, 16);
          if (l16 == 0) s_edot[k] = acc;
        }
      }
    }
    __syncthreads();   // JOIN
  }
}

extern "C" void kernel_launch(void* const* d_in, const int* in_sizes, int n_in,
                              void* d_out, int out_size, void* d_ws, size_t ws_size,
                              hipStream_t stream) {
  (void)in_sizes; (void)n_in; (void)out_size; (void)d_ws; (void)ws_size;
  const int*   marker_data   = (const int*)  d_in[0];
  const float* time_data     = (const float*)d_in[1];
  const float* mask_data     = (const float*)d_in[2];
  const float* embedding     = (const float*)d_in[3];
  const int*   neighbor_list = (const int*)  d_in[4];
  const float* neighbor_prob = (const float*)d_in[5];
  const float* W_te   = (const float*)d_in[6];
  const float* b_te   = (const float*)d_in[7];
  const float* W_el   = (const float*)d_in[8];
  const float* b_el   = (const float*)d_in[9];
  const float* W_ih   = (const float*)d_in[10];
  const float* b_ih   = (const float*)d_in[11];
  const float* W_hh   = (const float*)d_in[12];
  const float* b_hh   = (const float*)d_in[13];
  const float* W_time = (const float*)d_in[14];
  const float* b_time = (const float*)d_in[15];
  const float* W_mk   = (const float*)d_in[16];
  const float* b_mk   = (const float*)d_in[17];
  float* out = (float*)d_out;

  hipLaunchKernelGGL(rnn_gen_kernel, dim3(BB), dim3(1024), 0, stream,
                     marker_data, time_data, mask_data, embedding,
                     neighbor_list, neighbor_prob,
                     W_te, b_te, W_el, b_el, W_ih, b_ih, W_hh, b_hh,
                     W_time, b_time, W_mk, b_mk, out);
}

// Round 8
// 4346.892 us; speedup vs baseline: 1.4026x; 1.4026x over previous
//
#include <hip/hip_runtime.h>
#include <stdint.h>
#include <stddef.h>

// Problem constants (match reference)
#define BB 128
#define SS 128
#define EE 256
#define DD 512
#define KK 16
#define LL 1906   // 1 + 127*15
#define RR 2033   // 1 + 127*16
#define NSTEP 127
#define NBLK 64   // 2 rows per block

// ---------------- JAX threefry2x32 (bit-exact, partitionable) ----------------
static __device__ __forceinline__ uint32_t rotl32(uint32_t v, int r) {
  return (v << r) | (v >> (32 - r));
}

static __device__ __forceinline__ void tf2x32(uint32_t k0, uint32_t k1,
                                              uint32_t x0, uint32_t x1,
                                              uint32_t &o0, uint32_t &o1) {
  uint32_t ks2 = k0 ^ k1 ^ 0x1BD11BDAu;
  x0 += k0; x1 += k1;
#define TFR(r) { x0 += x1; x1 = rotl32(x1, (r)); x1 ^= x0; }
  TFR(13) TFR(15) TFR(26) TFR(6)
  x0 += k1;  x1 += ks2 + 1u;
  TFR(17) TFR(29) TFR(16) TFR(24)
  x0 += ks2; x1 += k0 + 2u;
  TFR(13) TFR(15) TFR(26) TFR(6)
  x0 += k0;  x1 += k1 + 3u;
  TFR(17) TFR(29) TFR(16) TFR(24)
  x0 += k1;  x1 += ks2 + 4u;
  TFR(13) TFR(15) TFR(26) TFR(6)
  x0 += ks2; x1 += k0 + 5u;
#undef TFR
  o0 = x0; o1 = x1;
}

static __device__ __forceinline__ float jax_gumbel(uint32_t bits) {
  float f = __uint_as_float((bits >> 9) | 0x3F800000u) - 1.0f;
  float u = fmaxf(f, 1.17549435e-38f);
  return -logf(-logf(u));
}

// 4 FMAs: one vec scalar x one float4 of weights into 4 col-accumulators
#define FMA4(vc, wv, a0, a1, a2, a3)                              \
  a0 = fma((double)(vc), (double)(wv).x, a0);                     \
  a1 = fma((double)(vc), (double)(wv).y, a1);                     \
  a2 = fma((double)(vc), (double)(wv).z, a2);                     \
  a3 = fma((double)(vc), (double)(wv).w, a3);

// ---------------- persistent kernel: one block per TWO batch rows ----------------
__global__ __launch_bounds__(1024, 4) void rnn2_kernel(
    const int*   __restrict__ marker_data,   // (B,S) int32
    const float* __restrict__ time_data,     // (B,S)
    const float* __restrict__ mask_data,     // (B,S)
    const float* __restrict__ embedding,     // (50000,E)
    const int*   __restrict__ neighbor_list, // (50000,K) int32
    const float* __restrict__ neighbor_prob, // (50000,K)
    const float* __restrict__ W_te, const float* __restrict__ b_te,
    const float* __restrict__ W_el, const float* __restrict__ b_el,
    const float* __restrict__ W_ih, const float* __restrict__ b_ih,
    const float* __restrict__ W_hh, const float* __restrict__ b_hh,
    const float* __restrict__ W_time, const float* __restrict__ b_time,
    const float* __restrict__ W_mk, const float* __restrict__ b_mk,
    float* __restrict__ out)                 // 5 x (B,S) f32, concat
{
  __shared__ double s_pA[8][DD];    // 32 KB: row-A partials (el, then ih)
  __shared__ double s_pB[8][DD];    // 32 KB: row-B partials
  __shared__ double s_phA[4][DD];   // 16 KB: row-A W_hh partials (pipelined)
  __shared__ double s_phB[4][DD];   // 16 KB: row-B W_hh partials
  __shared__ float  s_prob[2][LL];
  __shared__ int    s_cand[2][LL];
  __shared__ float  s_nrec[2][RR];
  __shared__ float  s_vec[2][EE];
  __shared__ float  s_x[2][DD];
  __shared__ float  s_h[2][DD];
  __shared__ double s_edot[2][KK];
  __shared__ float  s_lastt[2];
  __shared__ int    s_chosen[2];

  const int bid  = blockIdx.x;
  const int tid  = threadIdx.x;
  const int lane = tid & 63;
  const int wv   = tid >> 6;        // wave id 0..15

  // ---- init sweeps
  for (int i = tid; i < LL; i += 1024) {
    s_prob[0][i] = 0.0f; s_prob[1][i] = 0.0f;
    s_cand[0][i] = 0;    s_cand[1][i] = 0;
  }
  for (int i = tid; i < RR; i += 1024) { s_nrec[0][i] = 1.0f; s_nrec[1][i] = 1.0f; }
  if (tid < DD) { s_h[0][tid] = 0.0f; s_h[1][tid] = 0.0f; }
  for (int i = tid; i < 4 * DD; i += 1024) {     // hh partials for h0 = 0
    ((double*)s_phA)[i] = 0.0; ((double*)s_phB)[i] = 0.0;
  }
  __syncthreads();

  // ---- prologue: col-0 outputs + state (threads 0,1) ; step-0 prep (waves 0,1)
  if (tid < 2) {
    int   r  = 2 * bid + tid;
    int   m0 = marker_data[r * SS];
    float t0 = time_data[r * SS];
    s_cand[tid][0] = m0; s_prob[tid][0] = 1.0f;
    s_chosen[tid] = 0; s_lastt[tid] = t0;
    out[0 * BB * SS + r * SS] = (float)m0;
    out[1 * BB * SS + r * SS] = t0;
    out[2 * BB * SS + r * SS] = mask_data[r * SS];
    out[3 * BB * SS + r * SS] = 1.0f;
    out[4 * BB * SS + r * SS] = 1.0f;
  }
  if (wv < 2) {
    // prep(t=0): vec, neighbor bookkeeping slots, e-dots — wave wv owns row r
    const int   r  = 2 * bid + wv;
    const int   m  = marker_data[r * SS];
    const float lt = time_data[r * SS];
#pragma unroll
    for (int k = 0; k < 4; ++k) {
      int e = lane + (k << 6);
      float te = __fadd_rn(__fmul_rn(lt, W_te[e]), b_te[e]);
      s_vec[wv][e] = __fadd_rn(embedding[(size_t)m * EE + e], __fmul_rn(0.1f, te));
    }
    int nb = 0;
    if (lane < KK) {
      nb = neighbor_list[(size_t)m * KK + lane];
      s_nrec[wv][1 + lane] = neighbor_prob[(size_t)m * KK + lane];
      if (lane >= 1) s_cand[wv][1 + lane - 1] = nb;
    }
    int nbk = __shfl(nb, lane >> 2);
    const float4* er = (const float4*)(embedding + (size_t)nbk * EE) + (lane & 3) * 16;
    const float4* wm = (const float4*)W_mk + (lane & 3) * 16;
    double acc = 0.0;
#pragma unroll
    for (int i = 0; i < 16; ++i) {
      float4 e4 = er[i], m4 = wm[i];
      acc = fma((double)e4.x, (double)m4.x, acc);
      acc = fma((double)e4.y, (double)m4.y, acc);
      acc = fma((double)e4.z, (double)m4.z, acc);
      acc = fma((double)e4.w, (double)m4.w, acc);
    }
    acc += __shfl_xor(acc, 1);
    acc += __shfl_xor(acc, 2);
    if ((lane & 3) == 0) s_edot[wv][lane >> 2] = acc;
  }
  __syncthreads();

  const int jg = tid & 127;    // float4 col-group: cols 4*jg..4*jg+3
  const int sl = tid >> 7;     // K-slice 0..7

  for (int t = 0; t < NSTEP; ++t) {
    // ---- EL: vec @ W_el, both rows per weight load (8 slices x 32 rows)
    {
      const int i0 = sl << 5;
      const float4* W4 = (const float4*)W_el + (size_t)i0 * 128 + jg;
      double a00=0,a01=0,a02=0,a03=0, a10=0,a11=0,a12=0,a13=0;
#pragma unroll 4
      for (int i = 0; i < 32; i += 4) {
        float4 w0 = W4[0], w1 = W4[128], w2 = W4[256], w3 = W4[384];
        W4 += 512;
        float4 v0 = *(const float4*)&s_vec[0][i0 + i];
        float4 v1 = *(const float4*)&s_vec[1][i0 + i];
        FMA4(v0.x, w0, a00,a01,a02,a03) FMA4(v0.y, w1, a00,a01,a02,a03)
        FMA4(v0.z, w2, a00,a01,a02,a03) FMA4(v0.w, w3, a00,a01,a02,a03)
        FMA4(v1.x, w0, a10,a11,a12,a13) FMA4(v1.y, w1, a10,a11,a12,a13)
        FMA4(v1.z, w2, a10,a11,a12,a13) FMA4(v1.w, w3, a10,a11,a12,a13)
      }
      double* pa = &s_pA[sl][4 * jg]; pa[0]=a00; pa[1]=a01; pa[2]=a02; pa[3]=a03;
      double* pb = &s_pB[sl][4 * jg]; pb[0]=a10; pb[1]=a11; pb[2]=a12; pb[3]=a13;
    }
    __syncthreads();

    // ---- combine x (thread -> (row, col))
    {
      const int r = tid >> 9, j = tid & 511;
      const double (*P)[DD] = r ? s_pB : s_pA;
      double d = ((P[0][j] + P[1][j]) + (P[2][j] + P[3][j]))
               + ((P[4][j] + P[5][j]) + (P[6][j] + P[7][j]));
      float z = __fadd_rn((float)d, b_el[j]);
      s_x[r][j] = (z >= 0.0f) ? z : __fmul_rn(0.01f, z);
    }
    __syncthreads();

    // ---- IH: x @ W_ih, both rows (8 slices x 64 rows)
    {
      const int i0 = sl << 6;
      const float4* W4 = (const float4*)W_ih + (size_t)i0 * 128 + jg;
      double a00=0,a01=0,a02=0,a03=0, a10=0,a11=0,a12=0,a13=0;
#pragma unroll 4
      for (int i = 0; i < 64; i += 4) {
        float4 w0 = W4[0], w1 = W4[128], w2 = W4[256], w3 = W4[384];
        W4 += 512;
        float4 v0 = *(const float4*)&s_x[0][i0 + i];
        float4 v1 = *(const float4*)&s_x[1][i0 + i];
        FMA4(v0.x, w0, a00,a01,a02,a03) FMA4(v0.y, w1, a00,a01,a02,a03)
        FMA4(v0.z, w2, a00,a01,a02,a03) FMA4(v0.w, w3, a00,a01,a02,a03)
        FMA4(v1.x, w0, a10,a11,a12,a13) FMA4(v1.y, w1, a10,a11,a12,a13)
        FMA4(v1.z, w2, a10,a11,a12,a13) FMA4(v1.w, w3, a10,a11,a12,a13)
      }
      double* pa = &s_pA[sl][4 * jg]; pa[0]=a00; pa[1]=a01; pa[2]=a02; pa[3]=a03;
      double* pb = &s_pB[sl][4 * jg]; pb[0]=a10; pb[1]=a11; pb[2]=a12; pb[3]=a13;
    }
    __syncthreads();

    // ---- combine h = tanh(((ih + b_ih) + hh) + b_hh); hh partials pipelined
    {
      const int r = tid >> 9, j = tid & 511;
      const double (*P)[DD]  = r ? s_pB : s_pA;
      const double (*PH)[DD] = r ? s_phB : s_phA;
      double ih = ((P[0][j] + P[1][j]) + (P[2][j] + P[3][j]))
                + ((P[4][j] + P[5][j]) + (P[6][j] + P[7][j]));
      double hh = (PH[0][j] + PH[1][j]) + (PH[2][j] + PH[3][j]);
      float p = __fadd_rn(__fadd_rn(__fadd_rn((float)ih, b_ih[j]), (float)hh), b_hh[j]);
      s_h[r][j] = (float)tanh((double)p);
    }
    __syncthreads();

    // ---- F: waves 0,1 = per-row serial tails (wave-synchronous, NO barriers,
    //         NO spins); waves 8-15 = next step's W_hh stream (h-only dep).
    if (wv < 2) {
      const int r = 2 * bid + wv;
      // 1. h-dots (W_time, W_mk[E:]) — f64, xor-butterfly reduce
      double pt = 0.0, pm = 0.0;
#pragma unroll
      for (int k = 0; k < 8; ++k) {
        int e = lane + (k << 6);
        double hv = (double)s_h[wv][e];
        pt = fma(hv, (double)W_time[e], pt);
        pm = fma(hv, (double)W_mk[EE + e], pm);
      }
      for (int off = 32; off > 0; off >>= 1) {
        pt += __shfl_xor(pt, off);
        pm += __shfl_xor(pm, off);
      }
      // 2. step key (all lanes redundantly)
      uint32_t kk0, kk1;
      tf2x32(0u, 42u, 0u, (uint32_t)t, kk0, kk1);
      // 3. new_t (all lanes; same f32 op order as validated rounds)
      float td = __fadd_rn((float)pt, b_time[0]);
      float sp = __fadd_rn(fmaxf(td, 0.0f), log1pf(expf(-fabsf(td))));
      float nt = __fadd_rn(s_lastt[wv], sp);
      // 4. softmax + prob writes (lanes 0-15; exact f32 op order)
      if (lane < KK) {
        float sc = __fadd_rn((float)(s_edot[wv][lane] + pm), b_mk[0]);
        float mx = sc;
        for (int k = 0; k < KK; ++k) mx = fmaxf(mx, __shfl(sc, k));
        float ee = expf(__fsub_rn(sc, mx));
        float ssum = 0.0f;
        for (int k = 0; k < KK; ++k) ssum = __fadd_rn(ssum, __shfl(ee, k)); // ordered
        float cp = s_prob[wv][s_chosen[wv]];
        float at = __fmul_rn(cp, __fdiv_rn(ee, ssum));
        if (lane == 0) s_prob[wv][s_chosen[wv]] = at;
        else           s_prob[wv][1 + t * (KK - 1) + lane - 1] = at;
      }
      // 5. gumbel-argmax scan (all 64 lanes; same-wave LDS order guarantees
      //    the step-4 writes are visible)
      const int active = 16 + 15 * t;
      float bz = -3.0e38f;
      int   bi = 0x7FFFFFFF;
      for (int l = lane; l < active; l += 64) {
        uint32_t i = (uint32_t)(r * LL + l), o0, o1;
        tf2x32(kk0, kk1, 0u, i, o0, o1);
        float g  = jax_gumbel(o0 ^ o1);
        float pr = s_prob[wv][l];
        float z  = (pr > 0.0f) ? __fadd_rn(logf(fmaxf(pr, 1e-38f)), g)
                               : __fadd_rn(-1e30f, g);
        if (z > bz) { bz = z; bi = l; }   // ascending l => strict > keeps first
      }
      for (int off = 32; off > 0; off >>= 1) {
        float oz = __shfl_xor(bz, off);
        int   oi = __shfl_xor(bi, off);
        if (oz > bz || (oz == bz && oi < bi)) { bz = oz; bi = oi; }
      }
      // 6. finalize (winner known in all lanes)
      const int i0w = bi;
      const int nm  = s_cand[wv][i0w];
      if (lane == 0) {
        out[0 * BB * SS + r * SS + (t + 1)] = (float)nm;
        out[1 * BB * SS + r * SS + (t + 1)] = nt;
        out[2 * BB * SS + r * SS + (t + 1)] = (nt < 1000.0f) ? 1.0f : 0.0f;
        out[3 * BB * SS + r * SS + (t + 1)] = s_nrec[wv][i0w];
        out[4 * BB * SS + r * SS + (t + 1)] = s_prob[wv][i0w];
        s_chosen[wv] = i0w; s_lastt[wv] = nt;
      }
      // 7. prep(t+1): vec, bookkeeping, e-dots
      if (t + 1 < NSTEP) {
#pragma unroll
        for (int k = 0; k < 4; ++k) {
          int e = lane + (k << 6);
          float te = __fadd_rn(__fmul_rn(nt, W_te[e]), b_te[e]);
          s_vec[wv][e] = __fadd_rn(embedding[(size_t)nm * EE + e], __fmul_rn(0.1f, te));
        }
        int nb = 0;
        if (lane < KK) {
          nb = neighbor_list[(size_t)nm * KK + lane];
          s_nrec[wv][1 + (t + 1) * KK + lane] = neighbor_prob[(size_t)nm * KK + lane];
          if (lane >= 1) s_cand[wv][1 + (t + 1) * (KK - 1) + lane - 1] = nb;
        }
        int nbk = __shfl(nb, lane >> 2);
        const float4* er = (const float4*)(embedding + (size_t)nbk * EE) + (lane & 3) * 16;
        const float4* wm = (const float4*)W_mk + (lane & 3) * 16;
        double acc = 0.0;
#pragma unroll
        for (int i = 0; i < 16; ++i) {
          float4 e4 = er[i], m4 = wm[i];
          acc = fma((double)e4.x, (double)m4.x, acc);
          acc = fma((double)e4.y, (double)m4.y, acc);
          acc = fma((double)e4.z, (double)m4.z, acc);
          acc = fma((double)e4.w, (double)m4.w, acc);
        }
        acc += __shfl_xor(acc, 1);
        acc += __shfl_xor(acc, 2);
        if ((lane & 3) == 0) s_edot[wv][lane >> 2] = acc;
      }
    } else if (tid >= 512 && t + 1 < NSTEP) {
      // ---- W_hh stream for next step, both rows (4 slices x 128 rows)
      const int q  = tid - 512;
      const int j4 = q & 127;
      const int s4 = q >> 7;
      const int i0 = s4 << 7;
      const float4* W4 = (const float4*)W_hh + (size_t)i0 * 128 + j4;
      double a00=0,a01=0,a02=0,a03=0, a10=0,a11=0,a12=0,a13=0;
#pragma unroll 4
      for (int i = 0; i < 128; i += 4) {
        float4 w0 = W4[0], w1 = W4[128], w2 = W4[256], w3 = W4[384];
        W4 += 512;
        float4 v0 = *(const float4*)&s_h[0][i0 + i];
        float4 v1 = *(const float4*)&s_h[1][i0 + i];
        FMA4(v0.x, w0, a00,a01,a02,a03) FMA4(v0.y, w1, a00,a01,a02,a03)
        FMA4(v0.z, w2, a00,a01,a02,a03) FMA4(v0.w, w3, a00,a01,a02,a03)
        FMA4(v1.x, w0, a10,a11,a12,a13) FMA4(v1.y, w1, a10,a11,a12,a13)
        FMA4(v1.z, w2, a10,a11,a12,a13) FMA4(v1.w, w3, a10,a11,a12,a13)
      }
      double* pa = &s_phA[s4][4 * j4]; pa[0]=a00; pa[1]=a01; pa[2]=a02; pa[3]=a03;
      double* pb = &s_phB[s4][4 * j4]; pb[0]=a10; pb[1]=a11; pb[2]=a12; pb[3]=a13;
    }
    __syncthreads();   // JOIN
  }
}

extern "C" void kernel_launch(void* const* d_in, const int* in_sizes, int n_in,
                              void* d_out, int out_size, void* d_ws, size_t ws_size,
                              hipStream_t stream) {
  (void)in_sizes; (void)n_in; (void)out_size; (void)d_ws; (void)ws_size;
  const int*   marker_data   = (const int*)  d_in[0];
  const float* time_data     = (const float*)d_in[1];
  const float* mask_data     = (const float*)d_in[2];
  const float* embedding     = (const float*)d_in[3];
  const int*   neighbor_list = (const int*)  d_in[4];
  const float* neighbor_prob = (const float*)d_in[5];
  const float* W_te   = (const float*)d_in[6];
  const float* b_te   = (const float*)d_in[7];
  const float* W_el   = (const float*)d_in[8];
  const float* b_el   = (const float*)d_in[9];
  const float* W_ih   = (const float*)d_in[10];
  const float* b_ih   = (const float*)d_in[11];
  const float* W_hh   = (const float*)d_in[12];
  const float* b_hh   = (const float*)d_in[13];
  const float* W_time = (const float*)d_in[14];
  const float* b_time = (const float*)d_in[15];
  const float* W_mk   = (const float*)d_in[16];
  const float* b_mk   = (const float*)d_in[17];
  float* out = (float*)d_out;

  hipLaunchKernelGGL(rnn2_kernel, dim3(NBLK), dim3(1024), 0, stream,
                     marker_data, time_data, mask_data, embedding,
                     neighbor_list, neighbor_prob,
                     W_te, b_te, W_el, b_el, W_ih, b_ih, W_hh, b_hh,
                     W_time, b_time, W_mk, b_mk, out);
}